// Round 1
// baseline (1242.095 us; speedup 1.0000x reference)
//
#include <hip/hip_runtime.h>

// FlipFlopLoss forward DP on MI355X.
// new[p] = logaddexp(prev[p-1] + x[t][move_idx[p-1]], prev[p] + x[t][stay_idx[p]])
// 1 block per batch, 4 waves, 2 positions per thread, prev in registers.
// x staged via 8-deep global_load_lds ring with counted vmcnt (no vmcnt(0) drain).

constexpr int NT   = 4000;
constexpr int NB   = 128;
constexpr int NF   = 40;
constexpr int NPOS = 500;
constexpr int RBUF = 8;   // x ring slots (power of 2)
constexpr int PRE  = 7;   // prefetch distance = RBUF-1
constexpr float NEG = -1e30f;

__device__ __forceinline__ float logaddexp_f(float a, float b) {
    float mx = fmaxf(a, b);
    float mn = fminf(a, b);
    // log1p(exp(mn-mx)); exp underflows to 0 for mn-mx ~ -1e30, giving mx exactly.
    return mx + __logf(1.0f + __expf(mn - mx));
}

__global__ void __launch_bounds__(256, 1) flipflop_fwd(
    const float* __restrict__ x,         // [NT, NB, NF]
    const int*   __restrict__ move_idx,  // [NB, NPOS-1]
    const int*   __restrict__ stay_idx,  // [NB, NPOS]
    const int*   __restrict__ seqlens,   // [NB]
    float*       __restrict__ out)       // [NB]
{
    const int b    = blockIdx.x;
    const int tid  = threadIdx.x;
    const int lane = tid & 63;
    const int wave = tid >> 6;

    __shared__ float xbuf[RBUF][NF];   // x[t % RBUF][f]
    __shared__ float bnd[2][4];        // parity-double-buffered wave-boundary prev

    const int  p0     = tid * 2;
    const int  p1     = p0 + 1;
    const bool active = (p0 < NPOS);   // tid < 250

    // Per-thread gather indices (time-invariant).
    int s0 = 0, s1 = 0, m0 = 0, m1 = 0;
    if (active) {
        s0 = stay_idx[b * NPOS + p0];
        s1 = stay_idx[b * NPOS + p1];
        if (p0 >= 1) m0 = move_idx[b * (NPOS - 1) + p0 - 1];
        m1 = move_idx[b * (NPOS - 1) + p1 - 1];
    }
    const int sl = seqlens[b];

    if (tid < 8) bnd[tid >> 2][tid & 3] = NEG;

    float prev0 = (p0 == 0) ? 0.0f : NEG;
    float prev1 = NEG;

    // Per-lane global source: x[t, b, lane], advanced by t*NB*NF.
    const float* gx = x + (size_t)b * NF + lane;

    // Preload steps 0..PRE-1 into slots 0..PRE-1 (wave 0, lanes < NF).
    if (wave == 0 && lane < NF) {
        #pragma unroll
        for (int i = 0; i < PRE; ++i) {
            __builtin_amdgcn_global_load_lds(
                (const __attribute__((address_space(1))) void*)(gx + (size_t)i * (NB * NF)),
                (__attribute__((address_space(3))) void*)(&xbuf[i][0]),
                4, 0, 0);
        }
    }
    if (wave == 0) asm volatile("s_waitcnt vmcnt(6)");   // slot 0 landed
    asm volatile("s_waitcnt lgkmcnt(0)" ::: "memory");
    __builtin_amdgcn_s_barrier();
    asm volatile("" ::: "memory");

    int slot = 0;  // t % RBUF
    int par  = 0;  // t & 1
    for (int t = 0; t < NT; ++t) {
        const float* xs = &xbuf[slot][0];

        // prev[p0-1]: lane-1's prev1 within wave; wave boundary via LDS.
        float nbv = __shfl_up(prev1, 1);
        if (lane == 0 && wave > 0) nbv = bnd[par][wave - 1];

        float xs0 = xs[s0];
        float xm0 = xs[m0];
        float xs1 = xs[s1];
        float xm1 = xs[m1];

        float stay0 = xs0 + prev0;
        float move0 = xm0 + nbv;
        float stay1 = xs1 + prev1;
        float move1 = xm1 + prev0;   // uses OLD prev0

        float n0 = (tid == 0) ? stay0 : logaddexp_f(move0, stay0);
        float n1 = logaddexp_f(move1, stay1);
        prev0 = n0;
        prev1 = n1;

        // Publish boundary for step t+1.
        if (lane == 63) bnd[par ^ 1][wave] = prev1;

        // Prefetch x[t+PRE] into slot (t+PRE)%RBUF (== slot consumed at t-1).
        if (wave == 0) {
            if (lane < NF) {
                int tf = t + PRE;
                if (tf > NT - 1) tf = NT - 1;   // keep vmcnt cadence uniform
                __builtin_amdgcn_global_load_lds(
                    (const __attribute__((address_space(1))) void*)(gx + (size_t)tf * (NB * NF)),
                    (__attribute__((address_space(3))) void*)(&xbuf[(slot + PRE) & (RBUF - 1)][0]),
                    4, 0, 0);
            }
            asm volatile("s_waitcnt vmcnt(6)");  // load for step t+1 has landed
        }
        asm volatile("s_waitcnt lgkmcnt(0)" ::: "memory");
        __builtin_amdgcn_s_barrier();
        asm volatile("" ::: "memory");

        slot = (slot + 1) & (RBUF - 1);
        par ^= 1;
    }

    if (active) {
        const int pf = sl - 1;
        if (p0 == pf)      out[b] = -prev0 * (1.0f / float(NT));
        else if (p1 == pf) out[b] = -prev1 * (1.0f / float(NT));
    }
}

extern "C" void kernel_launch(void* const* d_in, const int* in_sizes, int n_in,
                              void* d_out, int out_size, void* d_ws, size_t ws_size,
                              hipStream_t stream) {
    const float* x        = (const float*)d_in[0];
    const int*   move_idx = (const int*)d_in[1];
    const int*   stay_idx = (const int*)d_in[2];
    const int*   seqlens  = (const int*)d_in[3];
    float*       out      = (float*)d_out;

    flipflop_fwd<<<dim3(NB), dim3(256), 0, stream>>>(x, move_idx, stay_idx, seqlens, out);
}

// Round 3
// 793.993 us; speedup vs baseline: 1.5644x; 1.5644x over previous
//
#include <hip/hip_runtime.h>

// FlipFlopLoss forward DP, round 3 (r2 + compile fix: __exp2f -> exp2f).
// new[p] = logaddexp(prev[p-1] + x[move_idx[p-1]], prev[p] + x[stay_idx[p]])
// Left-only dependency => halo decomposition:
//   2 waves/block, 4 positions/lane. Wave0 owns p=0..255, wave1 owns 256..499
//   and redundantly computes a ghost region p=244..255 whose validity shrinks
//   1 position/step; refresh from wave0 every 8 steps (8 <= 12 ghost depth).
//   => one s_barrier per 8 steps instead of per step.
// Log2-domain DP (native v_exp_f32/v_log_f32 are base-2); the SHARP*log2e
// scale folds into the adds as fmaf. x staged [t][f] via global_load_lds into
// a 4-slot per-wave ring, counted vmcnt(8), prefetch depth 2 (no vmcnt(0),
// no __syncthreads anywhere).

constexpr int NT   = 4000;
constexpr int NB   = 128;
constexpr int NF   = 40;
constexpr int NPOS = 500;
constexpr float C_SCALE   = 1.4426950408889634f;           // SHARP * log2(e)
constexpr float OUT_SCALE = -0.6931471805599453f / 4000.f; // -ln2 / (SHARP*NT)
constexpr float NEGF = -1e30f;

__device__ __forceinline__ float lae2(float A, float B) {
    // log2-domain logaddexp: max + log2(1 + exp2(min-max)).
    // exp2(-1e30) underflows to 0 cleanly; equal args give +1.0 (=log2 2). OK.
    float mx = fmaxf(A, B);
    float mn = fminf(A, B);
    return mx + __log2f(1.0f + exp2f(mn - mx));
}

__global__ void __launch_bounds__(128, 1) flipflop_fwd(
    const float* __restrict__ x,         // [NT, NB, NF]
    const int*   __restrict__ move_idx,  // [NB, NPOS-1]
    const int*   __restrict__ stay_idx,  // [NB, NPOS]
    const int*   __restrict__ seqlens,   // [NB]
    float*       __restrict__ out)       // [NB]
{
    const int b    = blockIdx.x;
    const int tid  = threadIdx.x;
    const int lane = tid & 63;
    const int w    = tid >> 6;

    // Per-wave private x ring: [wave][slot=4][t-within-block=4][f=40].
    __shared__ float xblk[2][4][4][NF];
    // Halo exchange buffer, double-buffered by exchange parity.
    __shared__ float ex[2][12];

    const int pbase = (w == 0) ? 4 * lane : 244 + 4 * lane;  // wave1 max: 244+252+3=499

    int sidx[4], midx[4];
    #pragma unroll
    for (int j = 0; j < 4; ++j) {
        int p = pbase + j;
        sidx[j] = stay_idx[b * NPOS + p];
        int pm = (p >= 1) ? p - 1 : 0;          // p==0: dummy, absorbed by -1e30 neighbor
        midx[j] = move_idx[b * (NPOS - 1) + pm];
    }

    float F0 = (pbase == 0) ? 0.0f : NEGF;
    float F1 = NEGF, F2 = NEGF, F3 = NEGF;

    // Staging source: x[t, b, lane] for lane < 40.
    const float* gx = x + (size_t)b * NF + lane;

    auto stage = [&](int blk) {
        if (lane < NF) {
            const int slot = blk & 3;
            #pragma unroll
            for (int i = 0; i < 4; ++i) {
                int t = blk * 4 + i;
                if (t > NT - 1) t = NT - 1;     // tail overrun guard, keeps vmcnt cadence
                __builtin_amdgcn_global_load_lds(
                    (const __attribute__((address_space(1))) void*)(gx + (size_t)t * (NB * NF)),
                    (__attribute__((address_space(3))) void*)(&xblk[w][slot][i][0]),
                    4, 0, 0);
            }
        }
    };

    // Prologue: blocks 0 and 1 in flight.
    stage(0);
    stage(1);

    auto body = [&](int ib) {
        stage(ib + 2);                                    // prefetch depth 2
        // Outstanding: blk ib+1 (4) + blk ib+2 (4) = 8 -> blk ib has landed.
        asm volatile("s_waitcnt vmcnt(8)" ::: "memory");

        const int slot = ib & 3;
        const float* xs = &xblk[w][slot][0][0];

        // Gather all 4 steps x 8 indices up front (ds_read2-mergeable pairs).
        float gs[4][4], gm[4][4];
        #pragma unroll
        for (int i = 0; i < 4; ++i) {
            #pragma unroll
            for (int j = 0; j < 4; ++j) {
                gs[j][i] = xs[i * NF + sidx[j]];
                gm[j][i] = xs[i * NF + midx[j]];
            }
        }

        #pragma unroll
        for (int i = 0; i < 4; ++i) {
            float nb = __shfl_up(F3, 1);
            if (lane == 0) nb = NEGF;   // wave0: true boundary; wave1: ghost edge (invalid anyway)
            float n0 = lae2(fmaf(gm[0][i], C_SCALE, nb), fmaf(gs[0][i], C_SCALE, F0));
            float n1 = lae2(fmaf(gm[1][i], C_SCALE, F0), fmaf(gs[1][i], C_SCALE, F1));
            float n2 = lae2(fmaf(gm[2][i], C_SCALE, F1), fmaf(gs[2][i], C_SCALE, F2));
            float n3 = lae2(fmaf(gm[3][i], C_SCALE, F2), fmaf(gs[3][i], C_SCALE, F3));
            F0 = n0; F1 = n1; F2 = n2; F3 = n3;
        }
    };

    auto exchange = [&](int ep) {
        // Wave0 publishes its exact p=244..255 (lanes 61..63); wave1 refreshes ghost.
        if (w == 0 && lane >= 61) {
            const int base = (lane - 61) * 4;
            ex[ep][base + 0] = F0; ex[ep][base + 1] = F1;
            ex[ep][base + 2] = F2; ex[ep][base + 3] = F3;
        }
        asm volatile("s_waitcnt lgkmcnt(0)" ::: "memory");
        __builtin_amdgcn_s_barrier();
        asm volatile("" ::: "memory");
        if (w == 1 && lane < 3) {
            const int base = lane * 4;
            F0 = ex[ep][base + 0]; F1 = ex[ep][base + 1];
            F2 = ex[ep][base + 2]; F3 = ex[ep][base + 3];
        }
    };

    for (int it = 0; it < NT / 16; ++it) {   // 250 iters x 16 steps
        const int ib = it * 4;
        body(ib);     body(ib + 1);  exchange(0);
        body(ib + 2); body(ib + 3);  exchange(1);
    }

    // out[b] = -fwd[sl-1] / (SHARP*NT); fwd = F * ln2.
    const int pf = seqlens[b] - 1;
    #pragma unroll
    for (int j = 0; j < 4; ++j) {
        const int p = pbase + j;
        const float Fv = (j == 0) ? F0 : (j == 1) ? F1 : (j == 2) ? F2 : F3;
        const bool own = (w == 0) ? true : (p >= 256);  // wave1 ghost copies excluded
        if (own && p == pf) out[b] = Fv * OUT_SCALE;
    }
}

extern "C" void kernel_launch(void* const* d_in, const int* in_sizes, int n_in,
                              void* d_out, int out_size, void* d_ws, size_t ws_size,
                              hipStream_t stream) {
    const float* x        = (const float*)d_in[0];
    const int*   move_idx = (const int*)d_in[1];
    const int*   stay_idx = (const int*)d_in[2];
    const int*   seqlens  = (const int*)d_in[3];
    float*       out      = (float*)d_out;

    flipflop_fwd<<<dim3(NB), dim3(128), 0, stream>>>(x, move_idx, stay_idx, seqlens, out);
}

// Round 5
// 509.826 us; speedup vs baseline: 2.4363x; 1.5574x over previous
//
#include <hip/hip_runtime.h>

// FlipFlopLoss forward DP, round 5.
// new[p] = logaddexp(prev[p-1] + x[move_idx[p-1]], prev[p] + x[stay_idx[p]])
//
// Structure: 1 block/batch, 4 waves x 2 positions/lane, overlap-4 tiling:
//   wave w covers p in [124w, 124w+127]  (wave0: 0..127, wave3: 372..499).
//   Lanes 0,1 of waves 1..3 are a 4-position ghost owned exactly by wave
//   w-1's lanes 62,63. Ghost corrupts 1 position/step => exchange+barrier
//   every 4 steps, refreshed from wave w-1's published exact values.
// Neighbor prev[p0-1] via DPP wave_shr:1 (old=-1e30 supplies the lane-0
//   boundary AND p==0 "no move-in" via exp2 underflow).
// x staged by wave0 only into a shared 8-block LDS ring (global_load_lds
//   width 16, lanes 0..9), counted vmcnt(16) before each barrier (never 0).
// Gathers for window w+1 are issued before window w's compute and pinned
//   into VGPRs (asm) so LDS latency hides under compute, not on the chain.
// Log2-domain DP: lae2(a,b) = max(a,b) + log2(1 + exp2(-|a-b|)).

constexpr int NT   = 4000;
constexpr int NB   = 128;
constexpr int NF   = 40;
constexpr int NPOS = 500;
constexpr int NWIN = NT / 4;      // 1000 windows of 4 steps
constexpr float C_SCALE   = 1.4426950408889634f;           // SHARP * log2(e)
constexpr float OUT_SCALE = -0.6931471805599453f / 4000.f; // -ln2 / (SHARP*NT)
constexpr float NEGF = -1e30f;

__device__ __forceinline__ float dpp_shr1(float v) {
    // lane i gets lane i-1's v; lane 0 keeps old = NEGF (bound_ctrl=0).
    int r = __builtin_amdgcn_update_dpp(
        __float_as_int(NEGF), __float_as_int(v),
        0x138 /*wave_shr:1*/, 0xF, 0xF, false);
    return __int_as_float(r);
}

__device__ __forceinline__ float lae2(float A, float B) {
    float mx = fmaxf(A, B);
    float d  = A - B;
    // exp2(-|d|): neg+abs fold into v_exp_f32 source modifiers.
    return mx + __log2f(1.0f + exp2f(-fabsf(d)));
}

__global__ void __launch_bounds__(256, 1) flipflop_fwd(
    const float* __restrict__ x,         // [NT, NB, NF]
    const int*   __restrict__ move_idx,  // [NB, NPOS-1]
    const int*   __restrict__ stay_idx,  // [NB, NPOS]
    const int*   __restrict__ seqlens,   // [NB]
    float*       __restrict__ out)       // [NB]
{
    const int b    = blockIdx.x;
    const int tid  = threadIdx.x;
    const int lane = tid & 63;
    const int wv   = tid >> 6;

    __shared__ float xring[8][4][NF];   // shared ring: [block%8][t%4][f]
    __shared__ float ex[2][3][4];       // halo: [window parity][src wave][4]

    // Overlap-4 tiling: wave w covers 124w .. 124w+127.
    const int pbase = 124 * wv + 2 * lane;
    const int p0 = pbase, p1 = pbase + 1;   // max = 372+126+1 = 499, in range

    const int sidx0 = stay_idx[b * NPOS + p0];
    const int sidx1 = stay_idx[b * NPOS + p1];
    const int midx0 = move_idx[b * (NPOS - 1) + ((p0 >= 1) ? p0 - 1 : 0)];
    const int midx1 = move_idx[b * (NPOS - 1) + p0];   // p1-1 == p0

    float F0 = (p0 == 0) ? 0.0f : NEGF;
    float F1 = NEGF;

    // Staging source: lanes 0..9 each load 16 B (4 floats) of x[t, b, :].
    const float* gxv = x + (size_t)b * NF + lane * 4;

    auto stage = [&](int blk) {   // call only under (wv == 0)
        if (lane < 10) {
            const int slot = blk & 7;
            #pragma unroll
            for (int i = 0; i < 4; ++i) {
                int t = blk * 4 + i;
                if (t > NT - 1) t = NT - 1;   // tail clamp keeps vmcnt cadence
                __builtin_amdgcn_global_load_lds(
                    (const __attribute__((address_space(1))) void*)(gxv + (size_t)t * (NB * NF)),
                    (__attribute__((address_space(3))) void*)(&xring[slot][i][0]),
                    16, 0, 0);
            }
        }
    };

    auto gather = [&](int blk, float (&g)[16]) {
        const float* xs = &xring[blk & 7][0][0];
        #pragma unroll
        for (int i = 0; i < 4; ++i) {
            g[4 * i + 0] = xs[i * NF + sidx0];
            g[4 * i + 1] = xs[i * NF + midx0];
            g[4 * i + 2] = xs[i * NF + sidx1];
            g[4 * i + 3] = xs[i * NF + midx1];
        }
    };

    auto pin = [&](float (&g)[16]) {
        #pragma unroll
        for (int i = 0; i < 16; i += 4)
            asm volatile("" : "+v"(g[i]), "+v"(g[i + 1]), "+v"(g[i + 2]), "+v"(g[i + 3]));
    };

    auto compute = [&](const float (&g)[16]) {
        #pragma unroll
        for (int i = 0; i < 4; ++i) {
            float nb = dpp_shr1(F1);                    // lane-1's F1 = p0-1
            float a0 = fmaf(g[4 * i + 1], C_SCALE, nb);
            float b0 = fmaf(g[4 * i + 0], C_SCALE, F0);
            float a1 = fmaf(g[4 * i + 3], C_SCALE, F0); // old F0
            float b1 = fmaf(g[4 * i + 2], C_SCALE, F1);
            F0 = lae2(a0, b0);
            F1 = lae2(a1, b1);
        }
    };

    auto syncpt = [&](int w) {
        const int par = w & 1;
        // Wave w (<3) lanes 62,63 hold p = 124(w+1) .. 124(w+1)+3.
        if (wv < 3 && lane >= 62) {
            ex[par][wv][(lane - 62) * 2 + 0] = F0;
            ex[par][wv][(lane - 62) * 2 + 1] = F1;
        }
        if (wv == 0) asm volatile("s_waitcnt vmcnt(16)" ::: "memory");
        asm volatile("s_waitcnt lgkmcnt(0)" ::: "memory");
        __builtin_amdgcn_s_barrier();
        asm volatile("" ::: "memory");
        if (wv >= 1 && lane < 2) {                      // refresh 4-pos ghost
            F0 = ex[par][wv - 1][lane * 2 + 0];
            F1 = ex[par][wv - 1][lane * 2 + 1];
        }
    };

    // Prologue: blocks 0..5 in flight; 0,1 landed before first window.
    if (wv == 0) {
        #pragma unroll
        for (int blk = 0; blk < 6; ++blk) stage(blk);
        asm volatile("s_waitcnt vmcnt(16)" ::: "memory");
    }
    asm volatile("s_waitcnt lgkmcnt(0)" ::: "memory");
    __builtin_amdgcn_s_barrier();
    asm volatile("" ::: "memory");

    float gA[16], gB[16];
    gather(0, gA);

    for (int w = 0; w < NWIN; w += 2) {
        // Invariant entering 1st half: blocks <= w+1 landed, w+2..w+5 in flight.
        if (wv == 0) stage(w + 6);
        gather(w + 1, gB);     // block w+1 landed; latency hides under compute
        compute(gA);
        pin(gB);
        syncpt(w);             // vmcnt(16): block w+2 landed

        if (wv == 0) stage(w + 7);
        gather(w + 2, gA);     // block w+2 landed
        compute(gB);
        pin(gA);
        syncpt(w + 1);         // vmcnt(16): block w+3 landed
    }

    // out[b] = -fwd[sl-1]/(SHARP*NT); fwd = F * ln2.
    // Final syncpt refreshed ghosts, but exclude them anyway; owned ranges
    // (wave0: 0..127, w>=1: 124w+4 .. 124w+127) tile 0..499 exactly.
    const int pf  = seqlens[b] - 1;
    const bool own = (wv == 0) || (lane >= 2);
    if (own) {
        if (p0 == pf)      out[b] = F0 * OUT_SCALE;
        else if (p1 == pf) out[b] = F1 * OUT_SCALE;
    }
}

extern "C" void kernel_launch(void* const* d_in, const int* in_sizes, int n_in,
                              void* d_out, int out_size, void* d_ws, size_t ws_size,
                              hipStream_t stream) {
    const float* x        = (const float*)d_in[0];
    const int*   move_idx = (const int*)d_in[1];
    const int*   stay_idx = (const int*)d_in[2];
    const int*   seqlens  = (const int*)d_in[3];
    float*       out      = (float*)d_out;

    flipflop_fwd<<<dim3(NB), dim3(256), 0, stream>>>(x, move_idx, stay_idx, seqlens, out);
}

// Round 6
// 373.950 us; speedup vs baseline: 3.3216x; 1.3634x over previous
//
#include <hip/hip_runtime.h>

// FlipFlopLoss forward DP, round 6.
// new[p] = logaddexp(prev[p-1] + x[move_idx[p-1]], prev[p] + x[stay_idx[p]])
//
// Tiling (identical to R5, which validated exactly): 1 block/batch, 4 waves
// x 2 positions/lane, overlap-4: wave w covers [124w, 124w+127]; lanes 0,1 of
// waves>=1 are ghost refreshed from wave w-1's lanes 62,63 every 4 steps.
// Neighbor via DPP wave_shr:1 (old=-1e30 = boundary + p==0 case).
//
// New in R6 (attacks the LDS pipe + gather sinking diagnosed in R5):
//  - Time-minor ring: xring[slot][f] = float4{ x[t0..t3, b, f] }. Per-window
//    gathers = 4 x ds_read_b128 per thread (was 16 x ds_read_b32).
//  - Transpose staged FOR FREE by global_load_lds per-lane SOURCE addressing:
//    instr k, lane l reads x[t0+(l&3), b, 16k+(l>>2)] -> linear LDS dst is
//    exactly [f][t]. 3 instrs/window, wave0 only. 8-slot ring, vmcnt(15)
//    (slot needed 5 windows after issue ~ covers HBM latency). Never vmcnt(0).
//  - Gathers for window w+1 issued as asm volatile ds_read_b128 (un-sinkable)
//    before window w's compute; static offset: immediates from 8x unroll.
//    lgkmcnt(0) + sched_barrier(0) before each barrier (rule: hipcc hoists
//    reg-only ops past inline-asm waits otherwise).

typedef float f32x4 __attribute__((ext_vector_type(4)));

constexpr int NT   = 4000;
constexpr int NB   = 128;
constexpr int NF   = 40;
constexpr int NPOS = 500;
constexpr int NWIN = NT / 4;      // 1000 windows of 4 steps
constexpr float C_SCALE   = 1.4426950408889634f;           // SHARP * log2(e)
constexpr float OUT_SCALE = -0.6931471805599453f / 4000.f; // -ln2 / (SHARP*NT)
constexpr float NEGF = -1e30f;

__device__ __forceinline__ float dpp_shr1(float v) {
    // lane i gets lane i-1's v; lane 0 keeps old = NEGF (bound_ctrl=0).
    int r = __builtin_amdgcn_update_dpp(
        __float_as_int(NEGF), __float_as_int(v),
        0x138 /*wave_shr:1*/, 0xF, 0xF, false);
    return __int_as_float(r);
}

__device__ __forceinline__ float lae2(float A, float B) {
    float mx = fmaxf(A, B);
    float d  = A - B;
    return mx + __log2f(1.0f + exp2f(-fabsf(d)));   // neg/abs fold into v_exp
}

__global__ void __launch_bounds__(256, 1) flipflop_fwd(
    const float* __restrict__ x,         // [NT, NB, NF]
    const int*   __restrict__ move_idx,  // [NB, NPOS-1]
    const int*   __restrict__ stay_idx,  // [NB, NPOS]
    const int*   __restrict__ seqlens,   // [NB]
    float*       __restrict__ out)       // [NB]
{
    const int b    = blockIdx.x;
    const int tid  = threadIdx.x;
    const int lane = tid & 63;
    const int wv   = tid >> 6;

    __shared__ f32x4 xring[8][NF];      // [slot][f] -> 4 t-values; 5120 B
    __shared__ float ex[2][3][4];       // halo: [parity][src wave][4]

    // ---- position mapping / DP state (identical to R5) ----
    const int pbase = 124 * wv + 2 * lane;
    const int p0 = pbase, p1 = pbase + 1;          // max 499

    const int sidx0 = stay_idx[b * NPOS + p0];
    const int sidx1 = stay_idx[b * NPOS + p1];
    const int midx0 = move_idx[b * (NPOS - 1) + ((p0 >= 1) ? p0 - 1 : 0)];
    const int midx1 = move_idx[b * (NPOS - 1) + p0];

    float F0 = (p0 == 0) ? 0.0f : NEGF;
    float F1 = NEGF;

    // ---- LDS gather addresses (byte): base + idx*16, slot via offset: imm ----
    unsigned ring_u = (unsigned)(unsigned long long)
        (__attribute__((address_space(3))) char*)&xring[0][0];
    const unsigned a_s0 = ring_u + (unsigned)sidx0 * 16u;
    const unsigned a_m0 = ring_u + (unsigned)midx0 * 16u;
    const unsigned a_s1 = ring_u + (unsigned)sidx1 * 16u;
    const unsigned a_m1 = ring_u + (unsigned)midx1 * 16u;

    f32x4 gbuf[2][4];   // [parity][s0,m0,s1,m1]; only static indices used

#define GATHER(SLOT, G) do {                                                        \
    asm volatile("ds_read_b128 %0, %1 offset:%c2"                                   \
                 : "=v"(gbuf[G][0]) : "v"(a_s0), "i"((SLOT) * 640));                \
    asm volatile("ds_read_b128 %0, %1 offset:%c2"                                   \
                 : "=v"(gbuf[G][1]) : "v"(a_m0), "i"((SLOT) * 640));                \
    asm volatile("ds_read_b128 %0, %1 offset:%c2"                                   \
                 : "=v"(gbuf[G][2]) : "v"(a_s1), "i"((SLOT) * 640));                \
    asm volatile("ds_read_b128 %0, %1 offset:%c2"                                   \
                 : "=v"(gbuf[G][3]) : "v"(a_m1), "i"((SLOT) * 640));                \
} while (0)

#define COMPUTE(G) do {                                                             \
    _Pragma("unroll")                                                               \
    for (int i = 0; i < 4; ++i) {                                                   \
        float nb = dpp_shr1(F1);                                                    \
        float a0 = fmaf(gbuf[G][1][i], C_SCALE, nb);                                \
        float b0 = fmaf(gbuf[G][0][i], C_SCALE, F0);                                \
        float a1 = fmaf(gbuf[G][3][i], C_SCALE, F0);                                \
        float b1 = fmaf(gbuf[G][2][i], C_SCALE, F1);                                \
        F0 = lae2(a0, b0);                                                          \
        F1 = lae2(a1, b1);                                                          \
    }                                                                               \
} while (0)

    // ---- staging (wave0): transpose via per-lane global source address ----
    // instr k, lane l: value v = 64k + l -> f = 16k + (l>>2), t-sub = l&3.
    // LDS dst (linear, base + lane*4) = slot base + v*4 = [f][t]  (f32x4 rows).
    const int tt = lane & 3;
    const float* gk0 = x + (size_t)b * NF + (lane >> 2);

    auto stagewin = [&](int w) {    // call under (wv == 0); 3 vmem instrs
        const int slot = w & 7;
        int t = w * 4 + tt;
        if (t > NT - 1) t = NT - 1;                 // tail clamp, cadence uniform
        const size_t toff = (size_t)t * (NB * NF);
        auto dst = (__attribute__((address_space(3))) char*)&xring[slot][0];
        __builtin_amdgcn_global_load_lds(
            (const __attribute__((address_space(1))) void*)(gk0 + toff),
            (__attribute__((address_space(3))) void*)(dst), 4, 0, 0);
        __builtin_amdgcn_global_load_lds(
            (const __attribute__((address_space(1))) void*)(gk0 + 16 + toff),
            (__attribute__((address_space(3))) void*)(dst + 256), 4, 0, 0);
        if (lane < 32)
            __builtin_amdgcn_global_load_lds(
                (const __attribute__((address_space(1))) void*)(gk0 + 32 + toff),
                (__attribute__((address_space(3))) void*)(dst + 512), 4, 0, 0);
    };

    // ---- prologue: windows 0..6 staged (21 loads out); slots 0,1 landed ----
    if (wv == 0) {
        for (int s = 0; s < 7; ++s) stagewin(s);
    }
    asm volatile("s_waitcnt vmcnt(15)" ::: "memory");
    asm volatile("s_waitcnt lgkmcnt(0)" ::: "memory");
    __builtin_amdgcn_sched_barrier(0);
    __builtin_amdgcn_s_barrier();
    asm volatile("" ::: "memory");

    GATHER(0, 0);   // window 0's operands from slot 0

    // ---- main loop: 125 iterations x 8 windows (slot/parity static) ----
    // Body(w) invariant at entry: slots w+2..w+6 outstanding (15 loads);
    // slot w+1 landed & published; gbuf[w&1] holds window w's operands.
#define BODY(W) do {                                                               \
    const int w_ = wbase + (W);                                                     \
    if (wv == 0) stagewin(w_ + 7);                      /* -> 18 outstanding */     \
    GATHER(((W) + 1) & 7, ((W) + 1) & 1);               /* slot w+1: landed */      \
    COMPUTE((W) & 1);                                                               \
    if (wv < 3 && lane >= 62) {                                                     \
        ex[(W) & 1][wv][(lane - 62) * 2 + 0] = F0;                                  \
        ex[(W) & 1][wv][(lane - 62) * 2 + 1] = F1;                                  \
    }                                                                               \
    asm volatile("s_waitcnt vmcnt(15)" ::: "memory");   /* slot w+2 landed */       \
    asm volatile("s_waitcnt lgkmcnt(0)" ::: "memory");  /* gathers+ex done */       \
    __builtin_amdgcn_sched_barrier(0);                                              \
    __builtin_amdgcn_s_barrier();                                                   \
    asm volatile("" ::: "memory");                                                  \
    if (wv >= 1 && lane < 2) {                                                      \
        F0 = ex[(W) & 1][wv - 1][lane * 2 + 0];                                     \
        F1 = ex[(W) & 1][wv - 1][lane * 2 + 1];                                     \
    }                                                                               \
} while (0)

    for (int wbase = 0; wbase < NWIN; wbase += 8) {
        BODY(0); BODY(1); BODY(2); BODY(3);
        BODY(4); BODY(5); BODY(6); BODY(7);
    }

#undef BODY
#undef COMPUTE
#undef GATHER

    // ---- output (identical to R5) ----
    const int pf  = seqlens[b] - 1;
    const bool own = (wv == 0) || (lane >= 2);
    if (own) {
        if (p0 == pf)      out[b] = F0 * OUT_SCALE;
        else if (p1 == pf) out[b] = F1 * OUT_SCALE;
    }
}

extern "C" void kernel_launch(void* const* d_in, const int* in_sizes, int n_in,
                              void* d_out, int out_size, void* d_ws, size_t ws_size,
                              hipStream_t stream) {
    const float* x        = (const float*)d_in[0];
    const int*   move_idx = (const int*)d_in[1];
    const int*   stay_idx = (const int*)d_in[2];
    const int*   seqlens  = (const int*)d_in[3];
    float*       out      = (float*)d_out;

    flipflop_fwd<<<dim3(NB), dim3(256), 0, stream>>>(x, move_idx, stay_idx, seqlens, out);
}

// Round 7
// 372.772 us; speedup vs baseline: 3.3321x; 1.0032x over previous
//
#include <hip/hip_runtime.h>

// FlipFlopLoss forward DP, round 6.
// new[p] = logaddexp(prev[p-1] + x[move_idx[p-1]], prev[p] + x[stay_idx[p]])
//
// Tiling (identical to R5, which validated exactly): 1 block/batch, 4 waves
// x 2 positions/lane, overlap-4: wave w covers [124w, 124w+127]; lanes 0,1 of
// waves>=1 are ghost refreshed from wave w-1's lanes 62,63 every 4 steps.
// Neighbor via DPP wave_shr:1 (old=-1e30 = boundary + p==0 case).
//
// New in R6 (attacks the LDS pipe + gather sinking diagnosed in R5):
//  - Time-minor ring: xring[slot][f] = float4{ x[t0..t3, b, f] }. Per-window
//    gathers = 4 x ds_read_b128 per thread (was 16 x ds_read_b32).
//  - Transpose staged FOR FREE by global_load_lds per-lane SOURCE addressing:
//    instr k, lane l reads x[t0+(l&3), b, 16k+(l>>2)] -> linear LDS dst is
//    exactly [f][t]. 3 instrs/window, wave0 only. 8-slot ring, vmcnt(15)
//    (slot needed 5 windows after issue ~ covers HBM latency). Never vmcnt(0).
//  - Gathers for window w+1 issued as asm volatile ds_read_b128 (un-sinkable)
//    before window w's compute; static offset: immediates from 8x unroll.
//    lgkmcnt(0) + sched_barrier(0) before each barrier (rule: hipcc hoists
//    reg-only ops past inline-asm waits otherwise).

typedef float f32x4 __attribute__((ext_vector_type(4)));

constexpr int NT   = 4000;
constexpr int NB   = 128;
constexpr int NF   = 40;
constexpr int NPOS = 500;
constexpr int NWIN = NT / 4;      // 1000 windows of 4 steps
constexpr float C_SCALE   = 1.4426950408889634f;           // SHARP * log2(e)
constexpr float OUT_SCALE = -0.6931471805599453f / 4000.f; // -ln2 / (SHARP*NT)
constexpr float NEGF = -1e30f;

__device__ __forceinline__ float dpp_shr1(float v) {
    // lane i gets lane i-1's v; lane 0 keeps old = NEGF (bound_ctrl=0).
    int r = __builtin_amdgcn_update_dpp(
        __float_as_int(NEGF), __float_as_int(v),
        0x138 /*wave_shr:1*/, 0xF, 0xF, false);
    return __int_as_float(r);
}

__device__ __forceinline__ float lae2(float A, float B) {
    float mx = fmaxf(A, B);
    float d  = A - B;
    return mx + __log2f(1.0f + exp2f(-fabsf(d)));   // neg/abs fold into v_exp
}

__global__ void __launch_bounds__(256, 1) flipflop_fwd(
    const float* __restrict__ x,         // [NT, NB, NF]
    const int*   __restrict__ move_idx,  // [NB, NPOS-1]
    const int*   __restrict__ stay_idx,  // [NB, NPOS]
    const int*   __restrict__ seqlens,   // [NB]
    float*       __restrict__ out)       // [NB]
{
    const int b    = blockIdx.x;
    const int tid  = threadIdx.x;
    const int lane = tid & 63;
    const int wv   = tid >> 6;

    __shared__ f32x4 xring[8][NF];      // [slot][f] -> 4 t-values; 5120 B
    __shared__ float ex[2][3][4];       // halo: [parity][src wave][4]

    // ---- position mapping / DP state (identical to R5) ----
    const int pbase = 124 * wv + 2 * lane;
    const int p0 = pbase, p1 = pbase + 1;          // max 499

    const int sidx0 = stay_idx[b * NPOS + p0];
    const int sidx1 = stay_idx[b * NPOS + p1];
    const int midx0 = move_idx[b * (NPOS - 1) + ((p0 >= 1) ? p0 - 1 : 0)];
    const int midx1 = move_idx[b * (NPOS - 1) + p0];

    float F0 = (p0 == 0) ? 0.0f : NEGF;
    float F1 = NEGF;

    // ---- LDS gather addresses (byte): base + idx*16, slot via offset: imm ----
    unsigned ring_u = (unsigned)(unsigned long long)
        (__attribute__((address_space(3))) char*)&xring[0][0];
    const unsigned a_s0 = ring_u + (unsigned)sidx0 * 16u;
    const unsigned a_m0 = ring_u + (unsigned)midx0 * 16u;
    const unsigned a_s1 = ring_u + (unsigned)sidx1 * 16u;
    const unsigned a_m1 = ring_u + (unsigned)midx1 * 16u;

    f32x4 gbuf[2][4];   // [parity][s0,m0,s1,m1]; only static indices used

#define GATHER(SLOT, G) do {                                                        \
    asm volatile("ds_read_b128 %0, %1 offset:%c2"                                   \
                 : "=v"(gbuf[G][0]) : "v"(a_s0), "i"((SLOT) * 640));                \
    asm volatile("ds_read_b128 %0, %1 offset:%c2"                                   \
                 : "=v"(gbuf[G][1]) : "v"(a_m0), "i"((SLOT) * 640));                \
    asm volatile("ds_read_b128 %0, %1 offset:%c2"                                   \
                 : "=v"(gbuf[G][2]) : "v"(a_s1), "i"((SLOT) * 640));                \
    asm volatile("ds_read_b128 %0, %1 offset:%c2"                                   \
                 : "=v"(gbuf[G][3]) : "v"(a_m1), "i"((SLOT) * 640));                \
} while (0)

#define COMPUTE(G) do {                                                             \
    _Pragma("unroll")                                                               \
    for (int i = 0; i < 4; ++i) {                                                   \
        float nb = dpp_shr1(F1);                                                    \
        float a0 = fmaf(gbuf[G][1][i], C_SCALE, nb);                                \
        float b0 = fmaf(gbuf[G][0][i], C_SCALE, F0);                                \
        float a1 = fmaf(gbuf[G][3][i], C_SCALE, F0);                                \
        float b1 = fmaf(gbuf[G][2][i], C_SCALE, F1);                                \
        F0 = lae2(a0, b0);                                                          \
        F1 = lae2(a1, b1);                                                          \
    }                                                                               \
} while (0)

    // ---- staging (wave0): transpose via per-lane global source address ----
    // instr k, lane l: value v = 64k + l -> f = 16k + (l>>2), t-sub = l&3.
    // LDS dst (linear, base + lane*4) = slot base + v*4 = [f][t]  (f32x4 rows).
    const int tt = lane & 3;
    const float* gk0 = x + (size_t)b * NF + (lane >> 2);

    auto stagewin = [&](int w) {    // call under (wv == 0); 3 vmem instrs
        const int slot = w & 7;
        int t = w * 4 + tt;
        if (t > NT - 1) t = NT - 1;                 // tail clamp, cadence uniform
        const size_t toff = (size_t)t * (NB * NF);
        auto dst = (__attribute__((address_space(3))) char*)&xring[slot][0];
        __builtin_amdgcn_global_load_lds(
            (const __attribute__((address_space(1))) void*)(gk0 + toff),
            (__attribute__((address_space(3))) void*)(dst), 4, 0, 0);
        __builtin_amdgcn_global_load_lds(
            (const __attribute__((address_space(1))) void*)(gk0 + 16 + toff),
            (__attribute__((address_space(3))) void*)(dst + 256), 4, 0, 0);
        if (lane < 32)
            __builtin_amdgcn_global_load_lds(
                (const __attribute__((address_space(1))) void*)(gk0 + 32 + toff),
                (__attribute__((address_space(3))) void*)(dst + 512), 4, 0, 0);
    };

    // ---- prologue: windows 0..6 staged (21 loads out); slots 0,1 landed ----
    if (wv == 0) {
        for (int s = 0; s < 7; ++s) stagewin(s);
    }
    asm volatile("s_waitcnt vmcnt(15)" ::: "memory");
    asm volatile("s_waitcnt lgkmcnt(0)" ::: "memory");
    __builtin_amdgcn_sched_barrier(0);
    __builtin_amdgcn_s_barrier();
    asm volatile("" ::: "memory");

    GATHER(0, 0);   // window 0's operands from slot 0

    // ---- main loop: 125 iterations x 8 windows (slot/parity static) ----
    // Body(w) invariant at entry: slots w+2..w+6 outstanding (15 loads);
    // slot w+1 landed & published; gbuf[w&1] holds window w's operands.
#define BODY(W) do {                                                               \
    const int w_ = wbase + (W);                                                     \
    if (wv == 0) stagewin(w_ + 7);                      /* -> 18 outstanding */     \
    GATHER(((W) + 1) & 7, ((W) + 1) & 1);               /* slot w+1: landed */      \
    COMPUTE((W) & 1);                                                               \
    if (wv < 3 && lane >= 62) {                                                     \
        ex[(W) & 1][wv][(lane - 62) * 2 + 0] = F0;                                  \
        ex[(W) & 1][wv][(lane - 62) * 2 + 1] = F1;                                  \
    }                                                                               \
    asm volatile("s_waitcnt vmcnt(15)" ::: "memory");   /* slot w+2 landed */       \
    asm volatile("s_waitcnt lgkmcnt(0)" ::: "memory");  /* gathers+ex done */       \
    __builtin_amdgcn_sched_barrier(0);                                              \
    __builtin_amdgcn_s_barrier();                                                   \
    asm volatile("" ::: "memory");                                                  \
    if (wv >= 1 && lane < 2) {                                                      \
        F0 = ex[(W) & 1][wv - 1][lane * 2 + 0];                                     \
        F1 = ex[(W) & 1][wv - 1][lane * 2 + 1];                                     \
    }                                                                               \
} while (0)

    for (int wbase = 0; wbase < NWIN; wbase += 8) {
        BODY(0); BODY(1); BODY(2); BODY(3);
        BODY(4); BODY(5); BODY(6); BODY(7);
    }

#undef BODY
#undef COMPUTE
#undef GATHER

    // ---- output (identical to R5) ----
    const int pf  = seqlens[b] - 1;
    const bool own = (wv == 0) || (lane >= 2);
    if (own) {
        if (p0 == pf)      out[b] = F0 * OUT_SCALE;
        else if (p1 == pf) out[b] = F1 * OUT_SCALE;
    }
}

extern "C" void kernel_launch(void* const* d_in, const int* in_sizes, int n_in,
                              void* d_out, int out_size, void* d_ws, size_t ws_size,
                              hipStream_t stream) {
    const float* x        = (const float*)d_in[0];
    const int*   move_idx = (const int*)d_in[1];
    const int*   stay_idx = (const int*)d_in[2];
    const int*   seqlens  = (const int*)d_in[3];
    float*       out      = (float*)d_out;

    flipflop_fwd<<<dim3(NB), dim3(256), 0, stream>>>(x, move_idx, stay_idx, seqlens, out);
}